// Round 16
// baseline (1005.725 us; speedup 1.0000x reference)
//
#include <hip/hip_runtime.h>
#include <hip/hip_bf16.h>
#include <math.h>

// Split-bf16 MFMA exact-KNN (K=32) + inverse-squared-distance weighting.
// points:[16384,64] features:[20000,64] targets:[20000] -> out:[16384]
//
// Round 16: cooperative chunk-walk on R15. Wave w owns subtile st=w>>2 and
// q-group g=w&3; ALL 16 waves walk every chunk together (pacing barrier
// every 2 chunks). The 4 waves sharing a subtile hit the same cache lines
// -> distinct L1-miss bytes/CU drop 4x (7.2 -> 1.8 MB). Same 8-MFMA chain
// per group as R15 (bit-identical s), same histogram tau, same CAP 352
// candidate pool + exact-rank phase 3.

#define NQ   16384
#define MM   20000
#define DD   64
#define KK   32
#define MPAD 20032
#define NCH  (MPAD / 64)   // 313
#define NW   16            // waves per block
#define QB   64            // queries per block
#define CAP  352           // E~156 (4096-sample tau) + 7 sigma
#define HS   264           // hist row stride (ints)
#define SCH  64            // sample chunks (rows 0..4095)

typedef __attribute__((ext_vector_type(8))) short bf16x8;
typedef __attribute__((ext_vector_type(4))) float f32x4;

// ---- workspace layout (bytes) ----
#define OFF_FH 0
#define SZ_FP  (MPAD * DD * 2)
#define OFF_FL (OFF_FH + SZ_FP)
#define OFF_FN (OFF_FL + SZ_FP)
#define SZ_FN  (MPAD * 4)
#define OFF_QH (OFF_FN + SZ_FN)
#define SZ_QP  (NQ * DD * 2)
#define OFF_QL (OFF_QH + SZ_QP)
#define OFF_QN (OFF_QL + SZ_QP)
#define SZ_QN  (NQ * 4)
#define WS_REQ (OFF_QN + SZ_QN)

__device__ __forceinline__ unsigned int bf16_rne(float x) {
    unsigned int xb = __float_as_uint(x);
    return (xb + 0x7fffu + ((xb >> 16) & 1u)) & 0xffff0000u;
}
__device__ __forceinline__ unsigned enc32(float f) {
    unsigned b = __float_as_uint(f);
    return (b & 0x80000000u) ? ~b : (b | 0x80000000u);
}
__device__ __forceinline__ float dec32(unsigned k) {
    unsigned b = (k & 0x80000000u) ? (k & 0x7FFFFFFFu) : ~k;
    return __uint_as_float(b);
}

__global__ void prep_split(const float* __restrict__ src,
                           unsigned short* __restrict__ ph,
                           unsigned short* __restrict__ pl,
                           float* __restrict__ nrm, int nrows_real) {
    const int e = blockIdx.x * 256 + threadIdx.x;
    const int m = e >> 6;
    const int lane = threadIdx.x & 63;
    const bool real = (m < nrows_real);
    float x = real ? src[e] : 0.f;
    unsigned int hb = bf16_rne(x);
    float xh = __uint_as_float(hb);
    unsigned int lb = bf16_rne(x - xh);
    ph[e] = (unsigned short)(hb >> 16);
    pl[e] = (unsigned short)(lb >> 16);
    float s = x * x;
    #pragma unroll
    for (int o = 32; o >= 1; o >>= 1) s += __shfl_xor(s, o);
    if (lane == 0) nrm[m] = real ? s : __builtin_inff();
}

// one subtile (st fixed per wave), ONE q-group: 5 loads, 8 MFMA.
// Chain order identical to R15's per-group chain -> bit-identical s.
#define SUBTILE1(c_, EPI_)                                                    \
  {                                                                           \
    const int rb_ = (c_) * 64 + st * 16;                                      \
    const unsigned short* phh = Fh + (size_t)(rb_ + q) * DD + kof;            \
    const unsigned short* pll = Fl + (size_t)(rb_ + q) * DD + kof;            \
    const bf16x8 Ah0 = *(const bf16x8*)(phh);                                 \
    const bf16x8 Ah1 = *(const bf16x8*)(phh + 32);                            \
    const bf16x8 Al0 = *(const bf16x8*)(pll);                                 \
    const bf16x8 Al1 = *(const bf16x8*)(pll + 32);                            \
    const f32x4  fnv = *(const f32x4*)(fn + rb_ + hgrp * 4);                  \
    const int rb4 = rb_ + hgrp * 4;                                           \
    f32x4 a = {0.f, 0.f, 0.f, 0.f};                                           \
    a = __builtin_amdgcn_mfma_f32_16x16x32_bf16(Ah0, qh0, a, 0, 0, 0);        \
    a = __builtin_amdgcn_mfma_f32_16x16x32_bf16(Ah1, qh1, a, 0, 0, 0);        \
    a = __builtin_amdgcn_mfma_f32_16x16x32_bf16(Ah0, ql0, a, 0, 0, 0);        \
    a = __builtin_amdgcn_mfma_f32_16x16x32_bf16(Ah1, ql1, a, 0, 0, 0);        \
    a = __builtin_amdgcn_mfma_f32_16x16x32_bf16(Al0, qh0, a, 0, 0, 0);        \
    a = __builtin_amdgcn_mfma_f32_16x16x32_bf16(Al1, qh1, a, 0, 0, 0);        \
    a = __builtin_amdgcn_mfma_f32_16x16x32_bf16(Al0, ql0, a, 0, 0, 0);        \
    a = __builtin_amdgcn_mfma_f32_16x16x32_bf16(Al1, ql1, a, 0, 0, 0);        \
    const float s0 = fnv[0] - 2.f * a[0];                                     \
    const float s1 = fnv[1] - 2.f * a[1];                                     \
    const float s2 = fnv[2] - 2.f * a[2];                                     \
    const float s3 = fnv[3] - 2.f * a[3];                                     \
    EPI_(s0, s1, s2, s3, rb4)                                                 \
  }

#define EPI_HTOP(s0_, s1_, s2_, s3_, rb4_) {                                  \
    (void)(rb4_);                                                             \
    atomicAdd(&hist[hrow + (enc32(s0_) >> 24)], 1);                           \
    atomicAdd(&hist[hrow + (enc32(s1_) >> 24)], 1);                           \
    atomicAdd(&hist[hrow + (enc32(s2_) >> 24)], 1);                           \
    atomicAdd(&hist[hrow + (enc32(s3_) >> 24)], 1);                           \
}

#define EPI_HMID(s0_, s1_, s2_, s3_, rb4_) {                                  \
    (void)(rb4_);                                                             \
    const unsigned bb_ = (unsigned)bstg;                                      \
    const unsigned k0_ = enc32(s0_), k1_ = enc32(s1_);                        \
    const unsigned k2_ = enc32(s2_), k3_ = enc32(s3_);                        \
    if ((k0_ >> 24) == bb_) atomicAdd(&hist[hrow + ((k0_ >> 16) & 0xFFu)], 1);\
    if ((k1_ >> 24) == bb_) atomicAdd(&hist[hrow + ((k1_ >> 16) & 0xFFu)], 1);\
    if ((k2_ >> 24) == bb_) atomicAdd(&hist[hrow + ((k2_ >> 16) & 0xFFu)], 1);\
    if ((k3_ >> 24) == bb_) atomicAdd(&hist[hrow + ((k3_ >> 16) & 0xFFu)], 1);\
}

#define EPI_GATE(s0_, s1_, s2_, s3_, rb4_) {                                  \
    const float sv_[4] = {s0_, s1_, s2_, s3_};                                \
    _Pragma("unroll")                                                         \
    for (int j_ = 0; j_ < 4; ++j_) {                                          \
      if (sv_[j_] <= tauR) {                                                  \
        const int p_ = atomicAdd(&cnt[qq], 1);                                \
        if (p_ < CAP) {                                                       \
          bufd[qq * CAP + p_] = sv_[j_];                                      \
          bufi[qq * CAP + p_] = (unsigned short)((rb4_) + j_);                \
        }                                                                     \
      }                                                                       \
    }                                                                         \
}

// wave-level select over hist[qq][0..255]: first bin where base+cum >= KK.
#define SELECT256(qq_, base_, SELB_, BELOW_) {                                 \
    const int b0_ = lane * 4;                                                  \
    const int h0_ = hist[(qq_) * HS + b0_ + 0];                                \
    const int h1_ = hist[(qq_) * HS + b0_ + 1];                                \
    const int h2_ = hist[(qq_) * HS + b0_ + 2];                                \
    const int h3_ = hist[(qq_) * HS + b0_ + 3];                                \
    const int c4_ = h0_ + h1_ + h2_ + h3_;                                     \
    int pref_ = c4_;                                                           \
    _Pragma("unroll")                                                          \
    for (int of_ = 1; of_ < 64; of_ <<= 1) {                                   \
        const int t_ = __shfl_up(pref_, of_);                                  \
        if (lane >= of_) pref_ += t_;                                          \
    }                                                                          \
    const unsigned long long mk_ = __ballot((base_) + pref_ >= KK);            \
    const int sel_ = __builtin_ctzll(mk_ | 0x8000000000000000ull);             \
    const int cb_  = __shfl(pref_ - c4_, sel_) + (base_);                      \
    const int g0_ = __shfl(h0_, sel_), g1_ = __shfl(h1_, sel_);                \
    const int g2_ = __shfl(h2_, sel_);                                         \
    int bs_, bl_;                                                              \
    if      (cb_ + g0_ >= KK)             { bs_ = 0; bl_ = cb_; }              \
    else if (cb_ + g0_ + g1_ >= KK)       { bs_ = 1; bl_ = cb_ + g0_; }        \
    else if (cb_ + g0_ + g1_ + g2_ >= KK) { bs_ = 2; bl_ = cb_ + g0_ + g1_; }  \
    else                                  { bs_ = 3; bl_ = cb_ + g0_ + g1_ + g2_; } \
    SELB_ = sel_ * 4 + bs_;                                                    \
    BELOW_ = bl_;                                                              \
}

__global__ __launch_bounds__(1024) void knn_coop64(
    const unsigned short* __restrict__ Fh, const unsigned short* __restrict__ Fl,
    const float* __restrict__ fn,
    const unsigned short* __restrict__ Qh, const unsigned short* __restrict__ Ql,
    const float* __restrict__ qn,
    const float* __restrict__ targets, float* __restrict__ out)
{
    __shared__ __align__(16) unsigned char pool[QB * CAP * 6];
    __shared__ float tau_f[QB];
    __shared__ int   cnt[QB];
    __shared__ int   bstar[QB];
    __shared__ int   cbel[QB];

    int*            hist = (int*)pool;
    float*          bufd = (float*)pool;
    unsigned short* bufi = (unsigned short*)(pool + QB * CAP * 4);

    const int tid  = threadIdx.x;
    const int lane = tid & 63;
    const int w    = tid >> 6;          // 0..15
    const int st   = w >> 2;            // subtile 0..3 (4 waves share it)
    const int g    = w & 3;             // q-group 0..3
    const int qbase = blockIdx.x * QB;
    const int q    = lane & 15;
    const int hgrp = lane >> 4;
    const int kof  = hgrp * 8;
    const int qq   = g * 16 + q;        // this lane's query (local)
    const int hrow = qq * HS;

    if (tid < QB) cnt[tid] = 0;
    for (int i = tid; i < QB * HS; i += 1024) hist[i] = 0;

    // stationary Q^T fragments, ONE query group (g)
    const int qrow = qbase + qq;
    const bf16x8 qh0 = *(const bf16x8*)(Qh + (size_t)qrow * DD + kof);
    const bf16x8 qh1 = *(const bf16x8*)(Qh + (size_t)qrow * DD + kof + 32);
    const bf16x8 ql0 = *(const bf16x8*)(Ql + (size_t)qrow * DD + kof);
    const bf16x8 ql1 = *(const bf16x8*)(Ql + (size_t)qrow * DD + kof + 32);
    __syncthreads();

    // ===== phase 1a: coarse histogram over sample chunks 0..63 =============
    for (int c = 0; c < SCH; ++c) {
        SUBTILE1(c, EPI_HTOP)
        if (c & 1) __syncthreads();     // pacing: keep waves chunk-aligned
    }
    __syncthreads();

    // ===== phase 1b: coarse select (wave w owns queries 4w..4w+3) ==========
    #pragma unroll
    for (int e = 0; e < 4; ++e) {
        const int qs = w * 4 + e;
        int sb, bl;
        SELECT256(qs, 0, sb, bl)
        if (lane == 0) { bstar[qs] = sb; cbel[qs] = bl; }
    }
    __syncthreads();

    const int bstg = bstar[qq];

    // ===== phase 1c: zero hist for fine pass ===============================
    for (int i = tid; i < QB * HS; i += 1024) hist[i] = 0;
    __syncthreads();

    // ===== phase 1d: fine histogram (only values in the coarse bin) ========
    for (int c = 0; c < SCH; ++c) {
        SUBTILE1(c, EPI_HMID)
        if (c & 1) __syncthreads();
    }
    __syncthreads();

    // ===== phase 1e: fine select -> tau ====================================
    #pragma unroll
    for (int e = 0; e < 4; ++e) {
        const int qs = w * 4 + e;
        int sb, bl;
        SELECT256(qs, cbel[qs], sb, bl)
        (void)bl;
        if (lane == 0) {
            const unsigned key16 = ((unsigned)bstar[qs] << 8) | (unsigned)sb;
            tau_f[qs] = (key16 >= 0xFFFFu) ? __builtin_inff()
                                           : dec32((key16 + 1u) << 16);
        }
    }
    __syncthreads();   // hist dead; candidate buffers take over the pool

    // ===== phase 2: cooperative full scan, gated LDS append ================
    const float tauR = tau_f[qq];
    for (int c = 0; c < NCH; ++c) {
        SUBTILE1(c, EPI_GATE)
        if (c & 1) __syncthreads();
    }
    __syncthreads();

    // ===== phase 3: exact rank + weighted sum (4 q per wave) ===============
    #pragma unroll
    for (int e = 0; e < 4; ++e) {
        const int q3 = w * 4 + e;
        const int n  = min(cnt[q3], CAP);
        const float qnv = qn[qbase + q3];

        float    ms[6]; unsigned kk[6]; unsigned short miu[6];
        #pragma unroll
        for (int u = 0; u < 6; ++u) {
            const int j = lane + u * 64;
            const bool v = (j < n);
            ms[u]  = v ? bufd[q3 * CAP + j] : __builtin_inff();
            miu[u] = v ? bufi[q3 * CAP + j] : (unsigned short)0xFFFFu;
            kk[u]  = enc32(ms[u]);
        }
        unsigned lo = 0;
        for (int bit = 31; bit >= 0; --bit) {
            const unsigned trial = lo | (1u << bit);
            int c = 0;
            #pragma unroll
            for (int u = 0; u < 6; ++u) c += (kk[u] < trial);
            #pragma unroll
            for (int o = 32; o >= 1; o >>= 1) c += __shfl_xor(c, o);
            if (c < KK) lo = trial;
        }
        int c0 = 0, tcnt = 0;
        #pragma unroll
        for (int u = 0; u < 6; ++u) { c0 += (kk[u] < lo); tcnt += (kk[u] == lo); }
        #pragma unroll
        for (int o = 32; o >= 1; o >>= 1) {
            c0 += __shfl_xor(c0, o); tcnt += __shfl_xor(tcnt, o);
        }
        const int kprime = KK - c0;
        unsigned ilo = 0xFFFFu;
        if (tcnt != kprime) {
            ilo = 0;
            for (int bit = 15; bit >= 0; --bit) {
                const unsigned trial = ilo | (1u << bit);
                int c = 0;
                #pragma unroll
                for (int u = 0; u < 6; ++u)
                    c += ((kk[u] == lo) && ((unsigned)miu[u] < trial));
                #pragma unroll
                for (int o = 32; o >= 1; o >>= 1) c += __shfl_xor(c, o);
                if (c < kprime) ilo = trial;
            }
        }
        float nume = 0.f, deno = 0.f;
        #pragma unroll
        for (int u = 0; u < 6; ++u) {
            const bool inc = (kk[u] < lo) ||
                             ((kk[u] == lo) && ((unsigned)miu[u] <= ilo));
            if (inc) {
                const float d2 = fmaxf(qnv + ms[u], 0.f);
                const float wv = 1.f / (d2 + 1e-4f);
                nume = fmaf(wv, targets[miu[u]], nume);
                deno += wv;
            }
        }
        #pragma unroll
        for (int o = 32; o >= 1; o >>= 1) {
            nume += __shfl_xor(nume, o);
            deno += __shfl_xor(deno, o);
        }
        if (lane == 0) out[qbase + q3] = nume / fmaxf(deno, 1e-9f);
    }
}

// ---------------- fallback: round-1 exact fp32 vector kernel ----------------
#define BQ 32
#define WQ 8
__global__ __launch_bounds__(256) void hp_knn_kernel(
    const float* __restrict__ points, const float* __restrict__ features,
    const float* __restrict__ targets, float* __restrict__ out)
{
    __shared__ __align__(16) float Qs[BQ][DD];
    __shared__ float qn_s[BQ];
    __shared__ float topd[BQ][KK];
    __shared__ int   topi[BQ][KK];
    const int tid = threadIdx.x, lane = tid & 63, wv = tid >> 6, qb = wv * WQ;
    {
        const float4* src = (const float4*)(points + (size_t)blockIdx.x * BQ * DD);
        float4* dst = (float4*)&Qs[0][0];
        #pragma unroll
        for (int i = 0; i < (BQ * DD / 4) / 256; ++i) dst[tid + i * 256] = src[tid + i * 256];
    }
    for (int i = tid; i < BQ * KK; i += 256) { (&topd[0][0])[i] = __builtin_inff(); (&topi[0][0])[i] = 0; }
    __syncthreads();
    if (tid < BQ) {
        float s = 0.f;
        #pragma unroll
        for (int d = 0; d < DD; ++d) s = fmaf(Qs[tid][d], Qs[tid][d], s);
        qn_s[tid] = s;
    }
    __syncthreads();
    for (int c = 0; c < (MM + 63) / 64; ++c) {
        const int m = c * 64 + lane, mc = (m < MM) ? m : (MM - 1);
        float f[DD];
        const float4* fr = (const float4*)(features + (size_t)mc * DD);
        #pragma unroll
        for (int b = 0; b < DD / 4; ++b) { float4 v = fr[b]; f[4*b]=v.x; f[4*b+1]=v.y; f[4*b+2]=v.z; f[4*b+3]=v.w; }
        float fnv = 0.f;
        #pragma unroll
        for (int d = 0; d < DD; ++d) fnv = fmaf(f[d], f[d], fnv);
        float d2v[WQ];
        #pragma unroll
        for (int qi = 0; qi < WQ; ++qi) {
            const float4* qr = (const float4*)&Qs[qb + qi][0];
            float a0=0,a1=0,a2=0,a3=0;
            #pragma unroll
            for (int b = 0; b < DD / 4; ++b) {
                float4 q4 = qr[b];
                a0 = fmaf(q4.x, f[4*b], a0); a1 = fmaf(q4.y, f[4*b+1], a1);
                a2 = fmaf(q4.z, f[4*b+2], a2); a3 = fmaf(q4.w, f[4*b+3], a3);
            }
            float d2 = fmaxf(qn_s[qb+qi] + fnv - 2.f*((a0+a1)+(a2+a3)), 0.f);
            d2v[qi] = (m < MM) ? d2 : __builtin_inff();
        }
        #pragma unroll
        for (int qi = 0; qi < WQ; ++qi) {
            const int q = qb + qi;
            unsigned long long ball = __ballot(d2v[qi] < topd[q][KK-1]);
            while (ball) {
                const int j = __builtin_ctzll(ball); ball &= ball - 1;
                const float dval = __shfl(d2v[qi], j); const int mval = c * 64 + j;
                if (lane < KK) {
                    const float cur = topd[q][lane];
                    if (cur > dval) {
                        const float pd = (lane > 0) ? topd[q][lane-1] : -1.f;
                        const int   pi = (lane > 0) ? topi[q][lane-1] : 0;
                        const bool tp = (pd > dval);
                        topd[q][lane] = tp ? pd : dval; topi[q][lane] = tp ? pi : mval;
                    }
                }
            }
        }
    }
    #pragma unroll
    for (int qi = 0; qi < WQ; ++qi) {
        const int q = qb + qi;
        float wsum = 0.f, wt = 0.f;
        if (lane < KK) {
            const float ww = 1.f / (topd[q][lane] + 1e-4f);
            wsum = ww; wt = ww * targets[topi[q][lane]];
        }
        #pragma unroll
        for (int o = 32; o >= 1; o >>= 1) { wsum += __shfl_xor(wsum, o); wt += __shfl_xor(wt, o); }
        if (lane == 0) out[(size_t)blockIdx.x * BQ + q] = wt / fmaxf(wsum, 1e-9f);
    }
}

extern "C" void kernel_launch(void* const* d_in, const int* in_sizes, int n_in,
                              void* d_out, int out_size, void* d_ws, size_t ws_size,
                              hipStream_t stream) {
    const float* points   = (const float*)d_in[0];
    const float* features = (const float*)d_in[1];
    const float* targets  = (const float*)d_in[2];
    float* out = (float*)d_out;

    if (ws_size < (size_t)WS_REQ) {
        hp_knn_kernel<<<dim3(NQ / BQ), dim3(256), 0, stream>>>(points, features, targets, out);
        return;
    }
    char* ws = (char*)d_ws;
    unsigned short* Fh = (unsigned short*)(ws + OFF_FH);
    unsigned short* Fl = (unsigned short*)(ws + OFF_FL);
    float*          fn = (float*)(ws + OFF_FN);
    unsigned short* Qh = (unsigned short*)(ws + OFF_QH);
    unsigned short* Ql = (unsigned short*)(ws + OFF_QL);
    float*          qnp= (float*)(ws + OFF_QN);

    prep_split<<<dim3(MPAD * DD / 256), dim3(256), 0, stream>>>(features, Fh, Fl, fn, MM);
    prep_split<<<dim3(NQ * DD / 256),  dim3(256), 0, stream>>>(points,   Qh, Ql, qnp, NQ);
    knn_coop64<<<dim3(NQ / QB), dim3(1024), 0, stream>>>(Fh, Fl, fn, Qh, Ql, qnp, targets, out);
}

// Round 17
// 328.494 us; speedup vs baseline: 3.0616x; 3.0616x over previous
//
#include <hip/hip_runtime.h>
#include <hip/hip_bf16.h>
#include <math.h>

// Split-bf16 MFMA exact-KNN (K=32) + inverse-squared-distance weighting.
// points:[16384,64] features:[20000,64] targets:[20000] -> out:[16384]
//
// Round 17 = validated Round 15 (315.8us) + ONE change: phase 2 pair-shares
// chunk streams WITHOUT barriers. Waves 2p,2p+1 walk chunks c=p,p+8,...;
// even wave does subtiles 0-1, odd wave subtiles 2-3. Distinct per-CU
// chunk streams 16->8 (halves per-XCD L2 request traffic if pairs stay
// co-scheduled); worst-case drift degenerates to R15 exactly. Numerics,
// tau, candidates, rank: bit-identical to R15.

#define NQ   16384
#define MM   20000
#define DD   64
#define KK   32
#define MPAD 20032
#define NCH  (MPAD / 64)   // 313
#define NW   16            // waves per block
#define QB   64            // queries per block
#define CAP  352           // E~156 (4096-sample tau) + 7 sigma
#define HS   264           // hist row stride (ints)

typedef __attribute__((ext_vector_type(8))) short bf16x8;
typedef __attribute__((ext_vector_type(4))) float f32x4;

// ---- workspace layout (bytes) ----
#define OFF_FH 0
#define SZ_FP  (MPAD * DD * 2)
#define OFF_FL (OFF_FH + SZ_FP)
#define OFF_FN (OFF_FL + SZ_FP)
#define SZ_FN  (MPAD * 4)
#define OFF_QH (OFF_FN + SZ_FN)
#define SZ_QP  (NQ * DD * 2)
#define OFF_QL (OFF_QH + SZ_QP)
#define OFF_QN (OFF_QL + SZ_QP)
#define SZ_QN  (NQ * 4)
#define WS_REQ (OFF_QN + SZ_QN)

__device__ __forceinline__ unsigned int bf16_rne(float x) {
    unsigned int xb = __float_as_uint(x);
    return (xb + 0x7fffu + ((xb >> 16) & 1u)) & 0xffff0000u;
}
__device__ __forceinline__ unsigned enc32(float f) {
    unsigned b = __float_as_uint(f);
    return (b & 0x80000000u) ? ~b : (b | 0x80000000u);
}
__device__ __forceinline__ float dec32(unsigned k) {
    unsigned b = (k & 0x80000000u) ? (k & 0x7FFFFFFFu) : ~k;
    return __uint_as_float(b);
}

__global__ void prep_split(const float* __restrict__ src,
                           unsigned short* __restrict__ ph,
                           unsigned short* __restrict__ pl,
                           float* __restrict__ nrm, int nrows_real) {
    const int e = blockIdx.x * 256 + threadIdx.x;
    const int m = e >> 6;
    const int lane = threadIdx.x & 63;
    const bool real = (m < nrows_real);
    float x = real ? src[e] : 0.f;
    unsigned int hb = bf16_rne(x);
    float xh = __uint_as_float(hb);
    unsigned int lb = bf16_rne(x - xh);
    ph[e] = (unsigned short)(hb >> 16);
    pl[e] = (unsigned short)(lb >> 16);
    float s = x * x;
    #pragma unroll
    for (int o = 32; o >= 1; o >>= 1) s += __shfl_xor(s, o);
    if (lane == 0) nrm[m] = real ? s : __builtin_inff();
}

// one subtile: 5 loads, 32 MFMA (4 groups x 8, one acc chain per group).
#define SUBTILE4(c_, t_, EPI_)                                                \
  {                                                                           \
    const int rb_ = (c_) * 64 + (t_) * 16;                                    \
    const unsigned short* phh = Fh + (size_t)(rb_ + q) * DD + kof;            \
    const unsigned short* pll = Fl + (size_t)(rb_ + q) * DD + kof;            \
    const bf16x8 Ah0 = *(const bf16x8*)(phh);                                 \
    const bf16x8 Ah1 = *(const bf16x8*)(phh + 32);                            \
    const bf16x8 Al0 = *(const bf16x8*)(pll);                                 \
    const bf16x8 Al1 = *(const bf16x8*)(pll + 32);                            \
    const f32x4  fnv = *(const f32x4*)(fn + rb_ + hgrp * 4);                  \
    const int rb4 = rb_ + hgrp * 4;                                           \
    _Pragma("unroll")                                                         \
    for (int g = 0; g < 4; ++g) {                                             \
      f32x4 a = {0.f, 0.f, 0.f, 0.f};                                         \
      a = __builtin_amdgcn_mfma_f32_16x16x32_bf16(Ah0, qh0[g], a, 0, 0, 0);   \
      a = __builtin_amdgcn_mfma_f32_16x16x32_bf16(Ah1, qh1[g], a, 0, 0, 0);   \
      a = __builtin_amdgcn_mfma_f32_16x16x32_bf16(Ah0, ql0[g], a, 0, 0, 0);   \
      a = __builtin_amdgcn_mfma_f32_16x16x32_bf16(Ah1, ql1[g], a, 0, 0, 0);   \
      a = __builtin_amdgcn_mfma_f32_16x16x32_bf16(Al0, qh0[g], a, 0, 0, 0);   \
      a = __builtin_amdgcn_mfma_f32_16x16x32_bf16(Al1, qh1[g], a, 0, 0, 0);   \
      a = __builtin_amdgcn_mfma_f32_16x16x32_bf16(Al0, ql0[g], a, 0, 0, 0);   \
      a = __builtin_amdgcn_mfma_f32_16x16x32_bf16(Al1, ql1[g], a, 0, 0, 0);   \
      const float s0 = fnv[0] - 2.f * a[0];                                   \
      const float s1 = fnv[1] - 2.f * a[1];                                   \
      const float s2 = fnv[2] - 2.f * a[2];                                   \
      const float s3 = fnv[3] - 2.f * a[3];                                   \
      EPI_(g, s0, s1, s2, s3, rb4)                                            \
    }                                                                         \
  }

#define EPI_HTOP(g_, s0_, s1_, s2_, s3_, rb4_) {                              \
    (void)(rb4_);                                                             \
    const int r_ = ((g_) * 16 + q) * HS;                                      \
    atomicAdd(&hist[r_ + (enc32(s0_) >> 24)], 1);                             \
    atomicAdd(&hist[r_ + (enc32(s1_) >> 24)], 1);                             \
    atomicAdd(&hist[r_ + (enc32(s2_) >> 24)], 1);                             \
    atomicAdd(&hist[r_ + (enc32(s3_) >> 24)], 1);                             \
}

#define EPI_HMID(g_, s0_, s1_, s2_, s3_, rb4_) {                              \
    (void)(rb4_);                                                             \
    const int r_ = ((g_) * 16 + q) * HS;                                      \
    const unsigned bb_ = (unsigned)bst[g_];                                   \
    const unsigned k0_ = enc32(s0_), k1_ = enc32(s1_);                        \
    const unsigned k2_ = enc32(s2_), k3_ = enc32(s3_);                        \
    if ((k0_ >> 24) == bb_) atomicAdd(&hist[r_ + ((k0_ >> 16) & 0xFFu)], 1);  \
    if ((k1_ >> 24) == bb_) atomicAdd(&hist[r_ + ((k1_ >> 16) & 0xFFu)], 1);  \
    if ((k2_ >> 24) == bb_) atomicAdd(&hist[r_ + ((k2_ >> 16) & 0xFFu)], 1);  \
    if ((k3_ >> 24) == bb_) atomicAdd(&hist[r_ + ((k3_ >> 16) & 0xFFu)], 1);  \
}

#define EPI_GATE(g_, s0_, s1_, s2_, s3_, rb4_) {                              \
    const float tq_ = tauR[g_];                                               \
    const int qq_ = (g_) * 16 + q;                                            \
    const float sv_[4] = {s0_, s1_, s2_, s3_};                                \
    _Pragma("unroll")                                                         \
    for (int j_ = 0; j_ < 4; ++j_) {                                          \
      if (sv_[j_] <= tq_) {                                                   \
        const int p_ = atomicAdd(&cnt[qq_], 1);                               \
        if (p_ < CAP) {                                                       \
          bufd[qq_ * CAP + p_] = sv_[j_];                                     \
          bufi[qq_ * CAP + p_] = (unsigned short)((rb4_) + j_);               \
        }                                                                     \
      }                                                                       \
    }                                                                         \
}

// wave-level select over hist[qq][0..255]: first bin where base+cum >= KK.
#define SELECT256(qq_, base_, SELB_, BELOW_) {                                 \
    const int b0_ = lane * 4;                                                  \
    const int h0_ = hist[(qq_) * HS + b0_ + 0];                                \
    const int h1_ = hist[(qq_) * HS + b0_ + 1];                                \
    const int h2_ = hist[(qq_) * HS + b0_ + 2];                                \
    const int h3_ = hist[(qq_) * HS + b0_ + 3];                                \
    const int c4_ = h0_ + h1_ + h2_ + h3_;                                     \
    int pref_ = c4_;                                                           \
    _Pragma("unroll")                                                          \
    for (int of_ = 1; of_ < 64; of_ <<= 1) {                                   \
        const int t_ = __shfl_up(pref_, of_);                                  \
        if (lane >= of_) pref_ += t_;                                          \
    }                                                                          \
    const unsigned long long mk_ = __ballot((base_) + pref_ >= KK);            \
    const int sel_ = __builtin_ctzll(mk_ | 0x8000000000000000ull);             \
    const int cb_  = __shfl(pref_ - c4_, sel_) + (base_);                      \
    const int g0_ = __shfl(h0_, sel_), g1_ = __shfl(h1_, sel_);                \
    const int g2_ = __shfl(h2_, sel_);                                         \
    int bs_, bl_;                                                              \
    if      (cb_ + g0_ >= KK)             { bs_ = 0; bl_ = cb_; }              \
    else if (cb_ + g0_ + g1_ >= KK)       { bs_ = 1; bl_ = cb_ + g0_; }        \
    else if (cb_ + g0_ + g1_ + g2_ >= KK) { bs_ = 2; bl_ = cb_ + g0_ + g1_; }  \
    else                                  { bs_ = 3; bl_ = cb_ + g0_ + g1_ + g2_; } \
    SELB_ = sel_ * 4 + bs_;                                                    \
    BELOW_ = bl_;                                                              \
}

__global__ __launch_bounds__(1024) void knn_filter64(
    const unsigned short* __restrict__ Fh, const unsigned short* __restrict__ Fl,
    const float* __restrict__ fn,
    const unsigned short* __restrict__ Qh, const unsigned short* __restrict__ Ql,
    const float* __restrict__ qn,
    const float* __restrict__ targets, float* __restrict__ out)
{
    __shared__ __align__(16) unsigned char pool[QB * CAP * 6];
    __shared__ float tau_f[QB];
    __shared__ int   cnt[QB];
    __shared__ int   bstar[QB];
    __shared__ int   cbel[QB];

    int*            hist = (int*)pool;
    float*          bufd = (float*)pool;
    unsigned short* bufi = (unsigned short*)(pool + QB * CAP * 4);

    const int tid  = threadIdx.x;
    const int lane = tid & 63;
    const int w    = tid >> 6;          // 0..15
    const int qbase = blockIdx.x * QB;
    const int q    = lane & 15;
    const int hgrp = lane >> 4;
    const int kof  = hgrp * 8;

    if (tid < QB) cnt[tid] = 0;
    for (int i = tid; i < QB * HS; i += 1024) hist[i] = 0;

    // stationary Q^T fragments, 4 query groups
    bf16x8 qh0[4], qh1[4], ql0[4], ql1[4];
    #pragma unroll
    for (int g = 0; g < 4; ++g) {
        const int qrow = qbase + g * 16 + q;
        qh0[g] = *(const bf16x8*)(Qh + (size_t)qrow * DD + kof);
        qh1[g] = *(const bf16x8*)(Qh + (size_t)qrow * DD + kof + 32);
        ql0[g] = *(const bf16x8*)(Ql + (size_t)qrow * DD + kof);
        ql1[g] = *(const bf16x8*)(Ql + (size_t)qrow * DD + kof + 32);
    }
    __syncthreads();

    // ===== phase 1a: coarse histogram over sample chunks 0..63 =============
    #pragma unroll
    for (int cc = 0; cc < 4; ++cc) {
        const int chunk = w * 4 + cc;
        #pragma unroll
        for (int t = 0; t < 4; ++t) {
            SUBTILE4(chunk, t, EPI_HTOP)
        }
    }
    __syncthreads();

    // ===== phase 1b: coarse select (wave w owns queries 4w..4w+3) ==========
    #pragma unroll
    for (int e = 0; e < 4; ++e) {
        const int qq = w * 4 + e;
        int sb, bl;
        SELECT256(qq, 0, sb, bl)
        if (lane == 0) { bstar[qq] = sb; cbel[qq] = bl; }
    }
    __syncthreads();

    int bst[4];
    #pragma unroll
    for (int g = 0; g < 4; ++g) bst[g] = bstar[g * 16 + q];

    // ===== phase 1c: zero hist for fine pass ===============================
    for (int i = tid; i < QB * HS; i += 1024) hist[i] = 0;
    __syncthreads();

    // ===== phase 1d: fine histogram (only values in the coarse bin) ========
    #pragma unroll
    for (int cc = 0; cc < 4; ++cc) {
        const int chunk = w * 4 + cc;
        #pragma unroll
        for (int t = 0; t < 4; ++t) {
            SUBTILE4(chunk, t, EPI_HMID)
        }
    }
    __syncthreads();

    // ===== phase 1e: fine select -> tau ====================================
    #pragma unroll
    for (int e = 0; e < 4; ++e) {
        const int qq = w * 4 + e;
        int sb, bl;
        SELECT256(qq, cbel[qq], sb, bl)
        (void)bl;
        if (lane == 0) {
            const unsigned key16 = ((unsigned)bstar[qq] << 8) | (unsigned)sb;
            tau_f[qq] = (key16 >= 0xFFFFu) ? __builtin_inff()
                                           : dec32((key16 + 1u) << 16);
        }
    }
    __syncthreads();   // hist dead; candidate buffers take over the pool

    // ===== phase 2: pair-shared full scan (no barriers) ====================
    // Waves 2p,2p+1 walk the same chunk stream c=p,p+8,...; even wave does
    // subtiles 0-1, odd wave subtiles 2-3. 8 distinct streams per CU.
    float tauR[4];
    #pragma unroll
    for (int g = 0; g < 4; ++g) tauR[g] = tau_f[g * 16 + q];

    {
        const int cp = w >> 1;          // pair id 0..7
        const int tb = (w & 1) * 2;     // subtile base for this wave
        for (int c = cp; c < NCH; c += 8) {
            SUBTILE4(c, tb,     EPI_GATE)
            SUBTILE4(c, tb + 1, EPI_GATE)
        }
    }
    __syncthreads();

    // ===== phase 3: exact rank + weighted sum (4 q per wave) ===============
    #pragma unroll
    for (int e = 0; e < 4; ++e) {
        const int q3 = w * 4 + e;
        const int n  = min(cnt[q3], CAP);
        const float qnv = qn[qbase + q3];

        float    ms[6]; unsigned kk[6]; unsigned short miu[6];
        #pragma unroll
        for (int u = 0; u < 6; ++u) {
            const int j = lane + u * 64;
            const bool v = (j < n);
            ms[u]  = v ? bufd[q3 * CAP + j] : __builtin_inff();
            miu[u] = v ? bufi[q3 * CAP + j] : (unsigned short)0xFFFFu;
            kk[u]  = enc32(ms[u]);
        }
        unsigned lo = 0;
        for (int bit = 31; bit >= 0; --bit) {
            const unsigned trial = lo | (1u << bit);
            int c = 0;
            #pragma unroll
            for (int u = 0; u < 6; ++u) c += (kk[u] < trial);
            #pragma unroll
            for (int o = 32; o >= 1; o >>= 1) c += __shfl_xor(c, o);
            if (c < KK) lo = trial;
        }
        int c0 = 0, tcnt = 0;
        #pragma unroll
        for (int u = 0; u < 6; ++u) { c0 += (kk[u] < lo); tcnt += (kk[u] == lo); }
        #pragma unroll
        for (int o = 32; o >= 1; o >>= 1) {
            c0 += __shfl_xor(c0, o); tcnt += __shfl_xor(tcnt, o);
        }
        const int kprime = KK - c0;
        unsigned ilo = 0xFFFFu;
        if (tcnt != kprime) {
            ilo = 0;
            for (int bit = 15; bit >= 0; --bit) {
                const unsigned trial = ilo | (1u << bit);
                int c = 0;
                #pragma unroll
                for (int u = 0; u < 6; ++u)
                    c += ((kk[u] == lo) && ((unsigned)miu[u] < trial));
                #pragma unroll
                for (int o = 32; o >= 1; o >>= 1) c += __shfl_xor(c, o);
                if (c < kprime) ilo = trial;
            }
        }
        float nume = 0.f, deno = 0.f;
        #pragma unroll
        for (int u = 0; u < 6; ++u) {
            const bool inc = (kk[u] < lo) ||
                             ((kk[u] == lo) && ((unsigned)miu[u] <= ilo));
            if (inc) {
                const float d2 = fmaxf(qnv + ms[u], 0.f);
                const float wv = 1.f / (d2 + 1e-4f);
                nume = fmaf(wv, targets[miu[u]], nume);
                deno += wv;
            }
        }
        #pragma unroll
        for (int o = 32; o >= 1; o >>= 1) {
            nume += __shfl_xor(nume, o);
            deno += __shfl_xor(deno, o);
        }
        if (lane == 0) out[qbase + q3] = nume / fmaxf(deno, 1e-9f);
    }
}

// ---------------- fallback: round-1 exact fp32 vector kernel ----------------
#define BQ 32
#define WQ 8
__global__ __launch_bounds__(256) void hp_knn_kernel(
    const float* __restrict__ points, const float* __restrict__ features,
    const float* __restrict__ targets, float* __restrict__ out)
{
    __shared__ __align__(16) float Qs[BQ][DD];
    __shared__ float qn_s[BQ];
    __shared__ float topd[BQ][KK];
    __shared__ int   topi[BQ][KK];
    const int tid = threadIdx.x, lane = tid & 63, wv = tid >> 6, qb = wv * WQ;
    {
        const float4* src = (const float4*)(points + (size_t)blockIdx.x * BQ * DD);
        float4* dst = (float4*)&Qs[0][0];
        #pragma unroll
        for (int i = 0; i < (BQ * DD / 4) / 256; ++i) dst[tid + i * 256] = src[tid + i * 256];
    }
    for (int i = tid; i < BQ * KK; i += 256) { (&topd[0][0])[i] = __builtin_inff(); (&topi[0][0])[i] = 0; }
    __syncthreads();
    if (tid < BQ) {
        float s = 0.f;
        #pragma unroll
        for (int d = 0; d < DD; ++d) s = fmaf(Qs[tid][d], Qs[tid][d], s);
        qn_s[tid] = s;
    }
    __syncthreads();
    for (int c = 0; c < (MM + 63) / 64; ++c) {
        const int m = c * 64 + lane, mc = (m < MM) ? m : (MM - 1);
        float f[DD];
        const float4* fr = (const float4*)(features + (size_t)mc * DD);
        #pragma unroll
        for (int b = 0; b < DD / 4; ++b) { float4 v = fr[b]; f[4*b]=v.x; f[4*b+1]=v.y; f[4*b+2]=v.z; f[4*b+3]=v.w; }
        float fnv = 0.f;
        #pragma unroll
        for (int d = 0; d < DD; ++d) fnv = fmaf(f[d], f[d], fnv);
        float d2v[WQ];
        #pragma unroll
        for (int qi = 0; qi < WQ; ++qi) {
            const float4* qr = (const float4*)&Qs[qb + qi][0];
            float a0=0,a1=0,a2=0,a3=0;
            #pragma unroll
            for (int b = 0; b < DD / 4; ++b) {
                float4 q4 = qr[b];
                a0 = fmaf(q4.x, f[4*b], a0); a1 = fmaf(q4.y, f[4*b+1], a1);
                a2 = fmaf(q4.z, f[4*b+2], a2); a3 = fmaf(q4.w, f[4*b+3], a3);
            }
            float d2 = fmaxf(qn_s[qb+qi] + fnv - 2.f*((a0+a1)+(a2+a3)), 0.f);
            d2v[qi] = (m < MM) ? d2 : __builtin_inff();
        }
        #pragma unroll
        for (int qi = 0; qi < WQ; ++qi) {
            const int q = qb + qi;
            unsigned long long ball = __ballot(d2v[qi] < topd[q][KK-1]);
            while (ball) {
                const int j = __builtin_ctzll(ball); ball &= ball - 1;
                const float dval = __shfl(d2v[qi], j); const int mval = c * 64 + j;
                if (lane < KK) {
                    const float cur = topd[q][lane];
                    if (cur > dval) {
                        const float pd = (lane > 0) ? topd[q][lane-1] : -1.f;
                        const int   pi = (lane > 0) ? topi[q][lane-1] : 0;
                        const bool tp = (pd > dval);
                        topd[q][lane] = tp ? pd : dval; topi[q][lane] = tp ? pi : mval;
                    }
                }
            }
        }
    }
    #pragma unroll
    for (int qi = 0; qi < WQ; ++qi) {
        const int q = qb + qi;
        float wsum = 0.f, wt = 0.f;
        if (lane < KK) {
            const float ww = 1.f / (topd[q][lane] + 1e-4f);
            wsum = ww; wt = ww * targets[topi[q][lane]];
        }
        #pragma unroll
        for (int o = 32; o >= 1; o >>= 1) { wsum += __shfl_xor(wsum, o); wt += __shfl_xor(wt, o); }
        if (lane == 0) out[(size_t)blockIdx.x * BQ + q] = wt / fmaxf(wsum, 1e-9f);
    }
}

extern "C" void kernel_launch(void* const* d_in, const int* in_sizes, int n_in,
                              void* d_out, int out_size, void* d_ws, size_t ws_size,
                              hipStream_t stream) {
    const float* points   = (const float*)d_in[0];
    const float* features = (const float*)d_in[1];
    const float* targets  = (const float*)d_in[2];
    float* out = (float*)d_out;

    if (ws_size < (size_t)WS_REQ) {
        hp_knn_kernel<<<dim3(NQ / BQ), dim3(256), 0, stream>>>(points, features, targets, out);
        return;
    }
    char* ws = (char*)d_ws;
    unsigned short* Fh = (unsigned short*)(ws + OFF_FH);
    unsigned short* Fl = (unsigned short*)(ws + OFF_FL);
    float*          fn = (float*)(ws + OFF_FN);
    unsigned short* Qh = (unsigned short*)(ws + OFF_QH);
    unsigned short* Ql = (unsigned short*)(ws + OFF_QL);
    float*          qnp= (float*)(ws + OFF_QN);

    prep_split<<<dim3(MPAD * DD / 256), dim3(256), 0, stream>>>(features, Fh, Fl, fn, MM);
    prep_split<<<dim3(NQ * DD / 256),  dim3(256), 0, stream>>>(points,   Qh, Ql, qnp, NQ);
    knn_filter64<<<dim3(NQ / QB), dim3(1024), 0, stream>>>(Fh, Fl, fn, Qh, Ql, qnp, targets, out);
}

// Round 18
// 290.459 us; speedup vs baseline: 3.4625x; 1.1309x over previous
//
#include <hip/hip_runtime.h>
#include <hip/hip_bf16.h>
#include <math.h>

// Split-bf16 MFMA exact-KNN (K=32) + inverse-squared-distance weighting.
// points:[16384,64] features:[20000,64] targets:[20000] -> out:[16384]
//
// Round 18 = validated Round 15 (315.8us) + hi-plane-only sampling:
// the two tau-histogram passes compute s_h = fn - 2*dot_hh from Fh ONLY
// (2 MFMA/group, half the sample bytes); final tau inflated by DLT=1.0
// (>>7 sigma of the |s - s_h| error) so true-top-32 coverage holds.
// Phase 2/3 (exact s, gate, exact rank) bit-identical to R15.
// Byte model: 7.3 -> 6.25 MB/CU at the measured ~21.5 GB/s/CU MSHR wall.

#define NQ   16384
#define MM   20000
#define DD   64
#define KK   32
#define MPAD 20032
#define NCH  (MPAD / 64)   // 313
#define NW   16            // waves per block
#define QB   64            // queries per block
#define CAP  352           // E~185 (hi-only tau + delta) + ~6 sigma
#define HS   264           // hist row stride (ints)
#define DLT  1.0f          // tau inflation covering |s - s_h|

typedef __attribute__((ext_vector_type(8))) short bf16x8;
typedef __attribute__((ext_vector_type(4))) float f32x4;

// ---- workspace layout (bytes) ----
#define OFF_FH 0
#define SZ_FP  (MPAD * DD * 2)
#define OFF_FL (OFF_FH + SZ_FP)
#define OFF_FN (OFF_FL + SZ_FP)
#define SZ_FN  (MPAD * 4)
#define OFF_QH (OFF_FN + SZ_FN)
#define SZ_QP  (NQ * DD * 2)
#define OFF_QL (OFF_QH + SZ_QP)
#define OFF_QN (OFF_QL + SZ_QP)
#define SZ_QN  (NQ * 4)
#define WS_REQ (OFF_QN + SZ_QN)

__device__ __forceinline__ unsigned int bf16_rne(float x) {
    unsigned int xb = __float_as_uint(x);
    return (xb + 0x7fffu + ((xb >> 16) & 1u)) & 0xffff0000u;
}
__device__ __forceinline__ unsigned enc32(float f) {
    unsigned b = __float_as_uint(f);
    return (b & 0x80000000u) ? ~b : (b | 0x80000000u);
}
__device__ __forceinline__ float dec32(unsigned k) {
    unsigned b = (k & 0x80000000u) ? (k & 0x7FFFFFFFu) : ~k;
    return __uint_as_float(b);
}

__global__ void prep_split(const float* __restrict__ src,
                           unsigned short* __restrict__ ph,
                           unsigned short* __restrict__ pl,
                           float* __restrict__ nrm, int nrows_real) {
    const int e = blockIdx.x * 256 + threadIdx.x;
    const int m = e >> 6;
    const int lane = threadIdx.x & 63;
    const bool real = (m < nrows_real);
    float x = real ? src[e] : 0.f;
    unsigned int hb = bf16_rne(x);
    float xh = __uint_as_float(hb);
    unsigned int lb = bf16_rne(x - xh);
    ph[e] = (unsigned short)(hb >> 16);
    pl[e] = (unsigned short)(lb >> 16);
    float s = x * x;
    #pragma unroll
    for (int o = 32; o >= 1; o >>= 1) s += __shfl_xor(s, o);
    if (lane == 0) nrm[m] = real ? s : __builtin_inff();
}

// full-precision subtile: 5 loads, 32 MFMA (4 groups x 8) -> exact s
#define SUBTILE4(c_, t_, EPI_)                                                \
  {                                                                           \
    const int rb_ = (c_) * 64 + (t_) * 16;                                    \
    const unsigned short* phh = Fh + (size_t)(rb_ + q) * DD + kof;            \
    const unsigned short* pll = Fl + (size_t)(rb_ + q) * DD + kof;            \
    const bf16x8 Ah0 = *(const bf16x8*)(phh);                                 \
    const bf16x8 Ah1 = *(const bf16x8*)(phh + 32);                            \
    const bf16x8 Al0 = *(const bf16x8*)(pll);                                 \
    const bf16x8 Al1 = *(const bf16x8*)(pll + 32);                            \
    const f32x4  fnv = *(const f32x4*)(fn + rb_ + hgrp * 4);                  \
    const int rb4 = rb_ + hgrp * 4;                                           \
    _Pragma("unroll")                                                         \
    for (int g = 0; g < 4; ++g) {                                             \
      f32x4 a = {0.f, 0.f, 0.f, 0.f};                                         \
      a = __builtin_amdgcn_mfma_f32_16x16x32_bf16(Ah0, qh0[g], a, 0, 0, 0);   \
      a = __builtin_amdgcn_mfma_f32_16x16x32_bf16(Ah1, qh1[g], a, 0, 0, 0);   \
      a = __builtin_amdgcn_mfma_f32_16x16x32_bf16(Ah0, ql0[g], a, 0, 0, 0);   \
      a = __builtin_amdgcn_mfma_f32_16x16x32_bf16(Ah1, ql1[g], a, 0, 0, 0);   \
      a = __builtin_amdgcn_mfma_f32_16x16x32_bf16(Al0, qh0[g], a, 0, 0, 0);   \
      a = __builtin_amdgcn_mfma_f32_16x16x32_bf16(Al1, qh1[g], a, 0, 0, 0);   \
      a = __builtin_amdgcn_mfma_f32_16x16x32_bf16(Al0, ql0[g], a, 0, 0, 0);   \
      a = __builtin_amdgcn_mfma_f32_16x16x32_bf16(Al1, ql1[g], a, 0, 0, 0);   \
      const float s0 = fnv[0] - 2.f * a[0];                                   \
      const float s1 = fnv[1] - 2.f * a[1];                                   \
      const float s2 = fnv[2] - 2.f * a[2];                                   \
      const float s3 = fnv[3] - 2.f * a[3];                                   \
      EPI_(g, s0, s1, s2, s3, rb4)                                            \
    }                                                                         \
  }

// hi-plane-only subtile (sampling): 3 loads, 8 MFMA (4 groups x 2) -> s_h
#define SUBTILE4H(c_, t_, EPI_)                                               \
  {                                                                           \
    const int rb_ = (c_) * 64 + (t_) * 16;                                    \
    const unsigned short* phh = Fh + (size_t)(rb_ + q) * DD + kof;            \
    const bf16x8 Ah0 = *(const bf16x8*)(phh);                                 \
    const bf16x8 Ah1 = *(const bf16x8*)(phh + 32);                            \
    const f32x4  fnv = *(const f32x4*)(fn + rb_ + hgrp * 4);                  \
    const int rb4 = rb_ + hgrp * 4;                                           \
    _Pragma("unroll")                                                         \
    for (int g = 0; g < 4; ++g) {                                             \
      f32x4 a = {0.f, 0.f, 0.f, 0.f};                                         \
      a = __builtin_amdgcn_mfma_f32_16x16x32_bf16(Ah0, qh0[g], a, 0, 0, 0);   \
      a = __builtin_amdgcn_mfma_f32_16x16x32_bf16(Ah1, qh1[g], a, 0, 0, 0);   \
      const float s0 = fnv[0] - 2.f * a[0];                                   \
      const float s1 = fnv[1] - 2.f * a[1];                                   \
      const float s2 = fnv[2] - 2.f * a[2];                                   \
      const float s3 = fnv[3] - 2.f * a[3];                                   \
      EPI_(g, s0, s1, s2, s3, rb4)                                            \
    }                                                                         \
  }

#define EPI_HTOP(g_, s0_, s1_, s2_, s3_, rb4_) {                              \
    (void)(rb4_);                                                             \
    const int r_ = ((g_) * 16 + q) * HS;                                      \
    atomicAdd(&hist[r_ + (enc32(s0_) >> 24)], 1);                             \
    atomicAdd(&hist[r_ + (enc32(s1_) >> 24)], 1);                             \
    atomicAdd(&hist[r_ + (enc32(s2_) >> 24)], 1);                             \
    atomicAdd(&hist[r_ + (enc32(s3_) >> 24)], 1);                             \
}

#define EPI_HMID(g_, s0_, s1_, s2_, s3_, rb4_) {                              \
    (void)(rb4_);                                                             \
    const int r_ = ((g_) * 16 + q) * HS;                                      \
    const unsigned bb_ = (unsigned)bst[g_];                                   \
    const unsigned k0_ = enc32(s0_), k1_ = enc32(s1_);                        \
    const unsigned k2_ = enc32(s2_), k3_ = enc32(s3_);                        \
    if ((k0_ >> 24) == bb_) atomicAdd(&hist[r_ + ((k0_ >> 16) & 0xFFu)], 1);  \
    if ((k1_ >> 24) == bb_) atomicAdd(&hist[r_ + ((k1_ >> 16) & 0xFFu)], 1);  \
    if ((k2_ >> 24) == bb_) atomicAdd(&hist[r_ + ((k2_ >> 16) & 0xFFu)], 1);  \
    if ((k3_ >> 24) == bb_) atomicAdd(&hist[r_ + ((k3_ >> 16) & 0xFFu)], 1);  \
}

#define EPI_GATE(g_, s0_, s1_, s2_, s3_, rb4_) {                              \
    const float tq_ = tauR[g_];                                               \
    const int qq_ = (g_) * 16 + q;                                            \
    const float sv_[4] = {s0_, s1_, s2_, s3_};                                \
    _Pragma("unroll")                                                         \
    for (int j_ = 0; j_ < 4; ++j_) {                                          \
      if (sv_[j_] <= tq_) {                                                   \
        const int p_ = atomicAdd(&cnt[qq_], 1);                               \
        if (p_ < CAP) {                                                       \
          bufd[qq_ * CAP + p_] = sv_[j_];                                     \
          bufi[qq_ * CAP + p_] = (unsigned short)((rb4_) + j_);               \
        }                                                                     \
      }                                                                       \
    }                                                                         \
}

// wave-level select over hist[qq][0..255]: first bin where base+cum >= KK.
#define SELECT256(qq_, base_, SELB_, BELOW_) {                                 \
    const int b0_ = lane * 4;                                                  \
    const int h0_ = hist[(qq_) * HS + b0_ + 0];                                \
    const int h1_ = hist[(qq_) * HS + b0_ + 1];                                \
    const int h2_ = hist[(qq_) * HS + b0_ + 2];                                \
    const int h3_ = hist[(qq_) * HS + b0_ + 3];                                \
    const int c4_ = h0_ + h1_ + h2_ + h3_;                                     \
    int pref_ = c4_;                                                           \
    _Pragma("unroll")                                                          \
    for (int of_ = 1; of_ < 64; of_ <<= 1) {                                   \
        const int t_ = __shfl_up(pref_, of_);                                  \
        if (lane >= of_) pref_ += t_;                                          \
    }                                                                          \
    const unsigned long long mk_ = __ballot((base_) + pref_ >= KK);            \
    const int sel_ = __builtin_ctzll(mk_ | 0x8000000000000000ull);             \
    const int cb_  = __shfl(pref_ - c4_, sel_) + (base_);                      \
    const int g0_ = __shfl(h0_, sel_), g1_ = __shfl(h1_, sel_);                \
    const int g2_ = __shfl(h2_, sel_);                                         \
    int bs_, bl_;                                                              \
    if      (cb_ + g0_ >= KK)             { bs_ = 0; bl_ = cb_; }              \
    else if (cb_ + g0_ + g1_ >= KK)       { bs_ = 1; bl_ = cb_ + g0_; }        \
    else if (cb_ + g0_ + g1_ + g2_ >= KK) { bs_ = 2; bl_ = cb_ + g0_ + g1_; }  \
    else                                  { bs_ = 3; bl_ = cb_ + g0_ + g1_ + g2_; } \
    SELB_ = sel_ * 4 + bs_;                                                    \
    BELOW_ = bl_;                                                              \
}

__global__ __launch_bounds__(1024) void knn_filter64(
    const unsigned short* __restrict__ Fh, const unsigned short* __restrict__ Fl,
    const float* __restrict__ fn,
    const unsigned short* __restrict__ Qh, const unsigned short* __restrict__ Ql,
    const float* __restrict__ qn,
    const float* __restrict__ targets, float* __restrict__ out)
{
    __shared__ __align__(16) unsigned char pool[QB * CAP * 6];
    __shared__ float tau_f[QB];
    __shared__ int   cnt[QB];
    __shared__ int   bstar[QB];
    __shared__ int   cbel[QB];

    int*            hist = (int*)pool;
    float*          bufd = (float*)pool;
    unsigned short* bufi = (unsigned short*)(pool + QB * CAP * 4);

    const int tid  = threadIdx.x;
    const int lane = tid & 63;
    const int w    = tid >> 6;          // 0..15
    const int qbase = blockIdx.x * QB;
    const int q    = lane & 15;
    const int hgrp = lane >> 4;
    const int kof  = hgrp * 8;

    if (tid < QB) cnt[tid] = 0;
    for (int i = tid; i < QB * HS; i += 1024) hist[i] = 0;

    // stationary Q^T fragments, 4 query groups
    bf16x8 qh0[4], qh1[4], ql0[4], ql1[4];
    #pragma unroll
    for (int g = 0; g < 4; ++g) {
        const int qrow = qbase + g * 16 + q;
        qh0[g] = *(const bf16x8*)(Qh + (size_t)qrow * DD + kof);
        qh1[g] = *(const bf16x8*)(Qh + (size_t)qrow * DD + kof + 32);
        ql0[g] = *(const bf16x8*)(Ql + (size_t)qrow * DD + kof);
        ql1[g] = *(const bf16x8*)(Ql + (size_t)qrow * DD + kof + 32);
    }
    __syncthreads();

    // ===== phase 1a: coarse histogram (hi-plane s_h), sample chunks 0..63 ==
    #pragma unroll
    for (int cc = 0; cc < 4; ++cc) {
        const int chunk = w * 4 + cc;
        #pragma unroll
        for (int t = 0; t < 4; ++t) {
            SUBTILE4H(chunk, t, EPI_HTOP)
        }
    }
    __syncthreads();

    // ===== phase 1b: coarse select (wave w owns queries 4w..4w+3) ==========
    #pragma unroll
    for (int e = 0; e < 4; ++e) {
        const int qq = w * 4 + e;
        int sb, bl;
        SELECT256(qq, 0, sb, bl)
        if (lane == 0) { bstar[qq] = sb; cbel[qq] = bl; }
    }
    __syncthreads();

    int bst[4];
    #pragma unroll
    for (int g = 0; g < 4; ++g) bst[g] = bstar[g * 16 + q];

    // ===== phase 1c: zero hist for fine pass ===============================
    for (int i = tid; i < QB * HS; i += 1024) hist[i] = 0;
    __syncthreads();

    // ===== phase 1d: fine histogram (hi-plane s_h, coarse-bin gated) =======
    #pragma unroll
    for (int cc = 0; cc < 4; ++cc) {
        const int chunk = w * 4 + cc;
        #pragma unroll
        for (int t = 0; t < 4; ++t) {
            SUBTILE4H(chunk, t, EPI_HMID)
        }
    }
    __syncthreads();

    // ===== phase 1e: fine select -> tau (+DLT coverage margin) =============
    #pragma unroll
    for (int e = 0; e < 4; ++e) {
        const int qq = w * 4 + e;
        int sb, bl;
        SELECT256(qq, cbel[qq], sb, bl)
        (void)bl;
        if (lane == 0) {
            const unsigned key16 = ((unsigned)bstar[qq] << 8) | (unsigned)sb;
            tau_f[qq] = (key16 >= 0xFFFFu) ? __builtin_inff()
                                           : (dec32((key16 + 1u) << 16) + DLT);
        }
    }
    __syncthreads();   // hist dead; candidate buffers take over the pool

    // ===== phase 2: full scan (exact s), register-tau gated LDS append =====
    float tauR[4];
    #pragma unroll
    for (int g = 0; g < 4; ++g) tauR[g] = tau_f[g * 16 + q];

    for (int c = w; c < NCH; c += NW) {
        #pragma unroll
        for (int t = 0; t < 4; ++t) {
            SUBTILE4(c, t, EPI_GATE)
        }
    }
    __syncthreads();

    // ===== phase 3: exact rank + weighted sum (4 q per wave) ===============
    #pragma unroll
    for (int e = 0; e < 4; ++e) {
        const int q3 = w * 4 + e;
        const int n  = min(cnt[q3], CAP);
        const float qnv = qn[qbase + q3];

        float    ms[6]; unsigned kk[6]; unsigned short miu[6];
        #pragma unroll
        for (int u = 0; u < 6; ++u) {
            const int j = lane + u * 64;
            const bool v = (j < n);
            ms[u]  = v ? bufd[q3 * CAP + j] : __builtin_inff();
            miu[u] = v ? bufi[q3 * CAP + j] : (unsigned short)0xFFFFu;
            kk[u]  = enc32(ms[u]);
        }
        unsigned lo = 0;
        for (int bit = 31; bit >= 0; --bit) {
            const unsigned trial = lo | (1u << bit);
            int c = 0;
            #pragma unroll
            for (int u = 0; u < 6; ++u) c += (kk[u] < trial);
            #pragma unroll
            for (int o = 32; o >= 1; o >>= 1) c += __shfl_xor(c, o);
            if (c < KK) lo = trial;
        }
        int c0 = 0, tcnt = 0;
        #pragma unroll
        for (int u = 0; u < 6; ++u) { c0 += (kk[u] < lo); tcnt += (kk[u] == lo); }
        #pragma unroll
        for (int o = 32; o >= 1; o >>= 1) {
            c0 += __shfl_xor(c0, o); tcnt += __shfl_xor(tcnt, o);
        }
        const int kprime = KK - c0;
        unsigned ilo = 0xFFFFu;
        if (tcnt != kprime) {
            ilo = 0;
            for (int bit = 15; bit >= 0; --bit) {
                const unsigned trial = ilo | (1u << bit);
                int c = 0;
                #pragma unroll
                for (int u = 0; u < 6; ++u)
                    c += ((kk[u] == lo) && ((unsigned)miu[u] < trial));
                #pragma unroll
                for (int o = 32; o >= 1; o >>= 1) c += __shfl_xor(c, o);
                if (c < kprime) ilo = trial;
            }
        }
        float nume = 0.f, deno = 0.f;
        #pragma unroll
        for (int u = 0; u < 6; ++u) {
            const bool inc = (kk[u] < lo) ||
                             ((kk[u] == lo) && ((unsigned)miu[u] <= ilo));
            if (inc) {
                const float d2 = fmaxf(qnv + ms[u], 0.f);
                const float wv = 1.f / (d2 + 1e-4f);
                nume = fmaf(wv, targets[miu[u]], nume);
                deno += wv;
            }
        }
        #pragma unroll
        for (int o = 32; o >= 1; o >>= 1) {
            nume += __shfl_xor(nume, o);
            deno += __shfl_xor(deno, o);
        }
        if (lane == 0) out[qbase + q3] = nume / fmaxf(deno, 1e-9f);
    }
}

// ---------------- fallback: round-1 exact fp32 vector kernel ----------------
#define BQ 32
#define WQ 8
__global__ __launch_bounds__(256) void hp_knn_kernel(
    const float* __restrict__ points, const float* __restrict__ features,
    const float* __restrict__ targets, float* __restrict__ out)
{
    __shared__ __align__(16) float Qs[BQ][DD];
    __shared__ float qn_s[BQ];
    __shared__ float topd[BQ][KK];
    __shared__ int   topi[BQ][KK];
    const int tid = threadIdx.x, lane = tid & 63, wv = tid >> 6, qb = wv * WQ;
    {
        const float4* src = (const float4*)(points + (size_t)blockIdx.x * BQ * DD);
        float4* dst = (float4*)&Qs[0][0];
        #pragma unroll
        for (int i = 0; i < (BQ * DD / 4) / 256; ++i) dst[tid + i * 256] = src[tid + i * 256];
    }
    for (int i = tid; i < BQ * KK; i += 256) { (&topd[0][0])[i] = __builtin_inff(); (&topi[0][0])[i] = 0; }
    __syncthreads();
    if (tid < BQ) {
        float s = 0.f;
        #pragma unroll
        for (int d = 0; d < DD; ++d) s = fmaf(Qs[tid][d], Qs[tid][d], s);
        qn_s[tid] = s;
    }
    __syncthreads();
    for (int c = 0; c < (MM + 63) / 64; ++c) {
        const int m = c * 64 + lane, mc = (m < MM) ? m : (MM - 1);
        float f[DD];
        const float4* fr = (const float4*)(features + (size_t)mc * DD);
        #pragma unroll
        for (int b = 0; b < DD / 4; ++b) { float4 v = fr[b]; f[4*b]=v.x; f[4*b+1]=v.y; f[4*b+2]=v.z; f[4*b+3]=v.w; }
        float fnv = 0.f;
        #pragma unroll
        for (int d = 0; d < DD; ++d) fnv = fmaf(f[d], f[d], fnv);
        float d2v[WQ];
        #pragma unroll
        for (int qi = 0; qi < WQ; ++qi) {
            const float4* qr = (const float4*)&Qs[qb + qi][0];
            float a0=0,a1=0,a2=0,a3=0;
            #pragma unroll
            for (int b = 0; b < DD / 4; ++b) {
                float4 q4 = qr[b];
                a0 = fmaf(q4.x, f[4*b], a0); a1 = fmaf(q4.y, f[4*b+1], a1);
                a2 = fmaf(q4.z, f[4*b+2], a2); a3 = fmaf(q4.w, f[4*b+3], a3);
            }
            float d2 = fmaxf(qn_s[qb+qi] + fnv - 2.f*((a0+a1)+(a2+a3)), 0.f);
            d2v[qi] = (m < MM) ? d2 : __builtin_inff();
        }
        #pragma unroll
        for (int qi = 0; qi < WQ; ++qi) {
            const int q = qb + qi;
            unsigned long long ball = __ballot(d2v[qi] < topd[q][KK-1]);
            while (ball) {
                const int j = __builtin_ctzll(ball); ball &= ball - 1;
                const float dval = __shfl(d2v[qi], j); const int mval = c * 64 + j;
                if (lane < KK) {
                    const float cur = topd[q][lane];
                    if (cur > dval) {
                        const float pd = (lane > 0) ? topd[q][lane-1] : -1.f;
                        const int   pi = (lane > 0) ? topi[q][lane-1] : 0;
                        const bool tp = (pd > dval);
                        topd[q][lane] = tp ? pd : dval; topi[q][lane] = tp ? pi : mval;
                    }
                }
            }
        }
    }
    #pragma unroll
    for (int qi = 0; qi < WQ; ++qi) {
        const int q = qb + qi;
        float wsum = 0.f, wt = 0.f;
        if (lane < KK) {
            const float ww = 1.f / (topd[q][lane] + 1e-4f);
            wsum = ww; wt = ww * targets[topi[q][lane]];
        }
        #pragma unroll
        for (int o = 32; o >= 1; o >>= 1) { wsum += __shfl_xor(wsum, o); wt += __shfl_xor(wt, o); }
        if (lane == 0) out[(size_t)blockIdx.x * BQ + q] = wt / fmaxf(wsum, 1e-9f);
    }
}

extern "C" void kernel_launch(void* const* d_in, const int* in_sizes, int n_in,
                              void* d_out, int out_size, void* d_ws, size_t ws_size,
                              hipStream_t stream) {
    const float* points   = (const float*)d_in[0];
    const float* features = (const float*)d_in[1];
    const float* targets  = (const float*)d_in[2];
    float* out = (float*)d_out;

    if (ws_size < (size_t)WS_REQ) {
        hp_knn_kernel<<<dim3(NQ / BQ), dim3(256), 0, stream>>>(points, features, targets, out);
        return;
    }
    char* ws = (char*)d_ws;
    unsigned short* Fh = (unsigned short*)(ws + OFF_FH);
    unsigned short* Fl = (unsigned short*)(ws + OFF_FL);
    float*          fn = (float*)(ws + OFF_FN);
    unsigned short* Qh = (unsigned short*)(ws + OFF_QH);
    unsigned short* Ql = (unsigned short*)(ws + OFF_QL);
    float*          qnp= (float*)(ws + OFF_QN);

    prep_split<<<dim3(MPAD * DD / 256), dim3(256), 0, stream>>>(features, Fh, Fl, fn, MM);
    prep_split<<<dim3(NQ * DD / 256),  dim3(256), 0, stream>>>(points,   Qh, Ql, qnp, NQ);
    knn_filter64<<<dim3(NQ / QB), dim3(1024), 0, stream>>>(Fh, Fl, fn, Qh, Ql, qnp, targets, out);
}